// Round 1
// baseline (278.865 us; speedup 1.0000x reference)
//
#include <hip/hip_runtime.h>

// LIF repeat-encoder:
//   in  [B=64, C=64, L=512] fp32
//   out [B=64, T=32, L=512, C=64] fp32 (spikes, 0.0 or 1.0)
// Recurrence per element x: v += (x - v)/2 ; s = (v >= 1) ; v = v*(1-s)
//
// R3: stream-contiguous writes. R2 measured ~3.0 TB/s effective write BW vs
// the harness fill's 6.0 TB/s on the identical path; R2's streams were 16-KB
// chunks at 128-KB t-stride from 512 drifting blocks. Here each block owns a
// CONTIGUOUS 512-KB output region (b, l-half, t-quarter) and sweeps it
// sequentially: 8 t-steps x 64 KB with no jumps -- memcpy/fill-shaped.
// Spikes depend only on x (hard reset to 0 restarts the recurrence), so a
// t-quarter block recomputes t < t0 silently in registers (cheap VALU).
// x and v are register-resident (32+32 floats/thread); x is staged once
// through an XOR-swizzled LDS transpose (2-way bank conflicts = free).
// NUMERICS: keep exactly v + (x - v)*0.5f everywhere (bit-exact vs ref).

constexpr int B = 64;
constexpr int C = 64;
constexpr int L = 512;
constexpr int T = 32;
constexpr int LC = L * C;   // floats per (b,t) slab
constexpr int LH = 256;     // l-rows per block (l-half)
constexpr int TQ = 8;       // t-steps written per block (t-quarter)

typedef float vf4 __attribute__((ext_vector_type(4)));

__global__ __launch_bounds__(512) void lif_repeat_kernel(
    const float* __restrict__ in, float* __restrict__ out) {
  __shared__ float lds[LH * C];   // 64 KB: x transposed [l_local][c], swizzled
  const int tid = threadIdx.x;
  const int bid = blockIdx.x;
  const int q  = bid & 3;          // t-quarter
  const int lh = (bid >> 2) & 1;   // l-half
  const int b  = bid >> 3;
  const int t0 = q * TQ;

  // ---- stage in[b][:, lh*256 .. +256) -> lds[l][c], XOR-swizzled columns.
  // Logical (l,c) lives at lds[l*64 + (c&3) + 4*(((c>>2) ^ ((l>>2)&15)) & 15)].
  {
    const int crow = tid >> 3;     // 0..63 : input channel
    const int q8   = tid & 7;
    const int cl = crow & 3;
    const int ch = crow >> 2;
    const float* ip = in + (size_t)b * (C * L) + (size_t)crow * L + lh * LH;
#pragma unroll
    for (int k = 0; k < 8; ++k) {
      const int lo = q8 * 4 + k * 32;            // local l, multiple of 4
      const vf4 xv = *(const vf4*)(ip + lo);
      // (l>>2)&15 == (q8 + 8k)&15 == q8 + 8*(k&1) for all i in 0..3
      const int sw = cl + 4 * ((ch ^ (q8 + 8 * (k & 1))) & 15);
#pragma unroll
      for (int i = 0; i < 4; ++i) {
        lds[(lo + i) * 64 + sw] = xv[i];         // 2-way bank conflict (free)
      }
    }
  }
  __syncthreads();

  // ---- thread owns 32 elements: (l_local = rr + 32*j, c = 4*c4 .. +3), j=0..7
  const int c4 = tid & 15;
  const int rr = tid >> 4;         // 0..31
  float x[8][4], v[8][4];
#pragma unroll
  for (int j = 0; j < 8; ++j) {
    const int ll = rr + 32 * j;
    const int g = c4 ^ ((ll >> 2) & 15);
    const vf4 xv = *(const vf4*)(lds + ll * 64 + 4 * g);
    x[j][0] = xv.x; x[j][1] = xv.y; x[j][2] = xv.z; x[j][3] = xv.w;
    v[j][0] = v[j][1] = v[j][2] = v[j][3] = 0.f;
  }

  // ---- silent recompute of t < t0 (identical update+reset sequence, no I/O)
  for (int t = 0; t < t0; ++t) {
#pragma unroll
    for (int j = 0; j < 8; ++j) {
#pragma unroll
      for (int i = 0; i < 4; ++i) {
        const float vv = v[j][i] + (x[j][i] - v[j][i]) * 0.5f;
        v[j][i] = (vv >= 1.0f) ? 0.0f : vv;
      }
    }
  }

  // ---- write phase: 8 t-steps, each 64 KB block-contiguous; the block's
  // whole 512-KB region is swept sequentially (no t_stride jumps).
  float* op = out + (size_t)b * (T * LC) + (size_t)t0 * LC
                  + (size_t)(lh * LH + rr) * C + c4 * 4;
#pragma unroll 2
  for (int tt = 0; tt < TQ; ++tt) {
#pragma unroll
    for (int j = 0; j < 8; ++j) {
      vf4 s;
#pragma unroll
      for (int i = 0; i < 4; ++i) {
        v[j][i] += (x[j][i] - v[j][i]) * 0.5f;
      }
      s.x = (v[j][0] >= 1.0f) ? 1.0f : 0.0f;
      s.y = (v[j][1] >= 1.0f) ? 1.0f : 0.0f;
      s.z = (v[j][2] >= 1.0f) ? 1.0f : 0.0f;
      s.w = (v[j][3] >= 1.0f) ? 1.0f : 0.0f;
      *(vf4*)(op + (size_t)(32 * j) * C) = s;    // 4 rows x 256 B / wave-instr
#pragma unroll
      for (int i = 0; i < 4; ++i) {
        v[j][i] = (v[j][i] >= 1.0f) ? 0.0f : v[j][i];
      }
    }
    op += LC;
  }
}

extern "C" void kernel_launch(void* const* d_in, const int* in_sizes, int n_in,
                              void* d_out, int out_size, void* d_ws, size_t ws_size,
                              hipStream_t stream) {
  const float* in = (const float*)d_in[0];
  float* out = (float*)d_out;
  const int grid = B * 2 * 4;   // (b, l-half, t-quarter) = 512 blocks
  lif_repeat_kernel<<<grid, 512, 0, stream>>>(in, out);
}

// Round 2
// 270.963 us; speedup vs baseline: 1.0292x; 1.0292x over previous
//
#include <hip/hip_runtime.h>

// LIF repeat-encoder:
//   in  [B=64, C=64, L=512] fp32
//   out [B=64, T=32, L=512, C=64] fp32 (spikes, 0.0 or 1.0)
// Recurrence per element x: v += (x - v)/2 ; s = (v >= 1) ; v = v*(1-s)
//
// R4: single-variable probe vs R2 — NON-TEMPORAL stores.
// R3 post-mortem: write-stream contiguity re-layout (512-KB/block sweep) was
// neutral/regressive -> stream shape is not the limiter. Kernel effective BW
// ~3.1 TB/s vs fill's 6.1 on the same path. Two models fit exactly:
//   A) RFO: store-miss line fetch doubles HBM traffic (512 MB/6.06 TB/s=84us
//      ~= measured 88us). Fill avoids it (FETCH~0) via streaming policy.
//   B) poison-fill drain tail (~288 MiB dirty L2+MALL) shares write BW.
// NT stores (no L2/MALL allocate) eliminate A, don't affect B.
// Structure is exactly R2 (the faster baseline); ONLY the store op changes.
// NUMERICS: keep exactly v + (x - v)*0.5f (spike flip at threshold = absmax).

constexpr int B = 64;
constexpr int C = 64;
constexpr int L = 512;
constexpr int T = 32;

typedef float vf4 __attribute__((ext_vector_type(4)));

__global__ __launch_bounds__(256) void lif_repeat_kernel(
    const float* __restrict__ in, float* __restrict__ out) {
  __shared__ float lds[64 * 64];   // [l_local][c], 16 KB
  const int tid = threadIdx.x;
  const int b  = blockIdx.x >> 3;          // 8 l-tiles per batch
  const int l0 = (blockIdx.x & 7) * 64;    // 64 l-positions per block

  // ---- coalesced global -> LDS staging (4 float4 loads per thread)
  {
    const int c = tid >> 2;  // 0..63
    const int q = tid & 3;
    const float* ip = in + (size_t)b * (C * L) + (size_t)c * L + l0;
#pragma unroll
    for (int k = 0; k < 4; ++k) {
      const int lo = q * 4 + k * 16;           // l offset, multiple of 4
      const vf4 v = *(const vf4*)(ip + lo);
      lds[(lo + 0) * 64 + c] = v.x;
      lds[(lo + 1) * 64 + c] = v.y;
      lds[(lo + 2) * 64 + c] = v.z;
      lds[(lo + 3) * 64 + c] = v.w;
    }
  }
  __syncthreads();

  // ---- thread owns 16 elements: (l = rr + 16*j, c = c4*4 .. +3), j=0..3
  const int c4 = tid & 15;
  const int rr = tid >> 4;   // 0..15; wave w covers rr in {4w..4w+3}
  float x[4][4], v[4][4];
#pragma unroll
  for (int j = 0; j < 4; ++j) {
    const vf4 xv = *(const vf4*)(lds + (rr + 16 * j) * 64 + c4 * 4);
    x[j][0] = xv.x; x[j][1] = xv.y; x[j][2] = xv.z; x[j][3] = xv.w;
    v[j][0] = v[j][1] = v[j][2] = v[j][3] = 0.f;
  }

  // Per (wave, j): 4 consecutive l-rows x 64 c = 1 KiB contiguous; per t the
  // block's 4 waves x 4 j cover 16 KB contiguous at out[b][t][l0..l0+63][*].
  float* const obase = out + (size_t)b * (T * L * C) + (size_t)l0 * C + c4 * 4;
  constexpr size_t t_stride = (size_t)L * C;  // floats per time step

#pragma unroll 2
  for (int t = 0; t < T; ++t) {
    float* ot = obase + (size_t)t * t_stride;
#pragma unroll
    for (int j = 0; j < 4; ++j) {
      vf4 s;
#pragma unroll
      for (int i = 0; i < 4; ++i) {
        v[j][i] += (x[j][i] - v[j][i]) * 0.5f;
      }
      s.x = (v[j][0] >= 1.0f) ? 1.0f : 0.0f;
      s.y = (v[j][1] >= 1.0f) ? 1.0f : 0.0f;
      s.z = (v[j][2] >= 1.0f) ? 1.0f : 0.0f;
      s.w = (v[j][3] >= 1.0f) ? 1.0f : 0.0f;
      // R4 change: streaming store — no L2/MALL allocate, no RFO.
      __builtin_nontemporal_store(s, (vf4*)(ot + (size_t)(rr + 16 * j) * C));
#pragma unroll
      for (int i = 0; i < 4; ++i) {
        v[j][i] = (v[j][i] >= 1.0f) ? 0.0f : v[j][i];
      }
    }
  }
}

extern "C" void kernel_launch(void* const* d_in, const int* in_sizes, int n_in,
                              void* d_out, int out_size, void* d_ws, size_t ws_size,
                              hipStream_t stream) {
  const float* in = (const float*)d_in[0];
  float* out = (float*)d_out;
  const int grid = B * (L / 64);  // 512 blocks
  lif_repeat_kernel<<<grid, 256, 0, stream>>>(in, out);
}